// Round 7
// baseline (95.593 us; speedup 1.0000x reference)
//
#include <hip/hip_runtime.h>
#include <hip/hip_bf16.h>

#define TABN 2048
#define NF 16

// ---------------------------------------------------------------------------
// Table: g(ds_clipped) = b + sum_f ws[f]*sin(ds/1024*2^f) + wc[f]*cos(...)
// over ds in [-4,4], TABN intervals. Entry k = {g(k), g(k+1)-g(k)}.
// sincosf only for f=0..7 (|a| <= 0.5 rad: fast path); f=8..15 via
// double-angle recurrence (err <= ~1e-4). Interp err at h=1/256: <= ~2e-3.
// ---------------------------------------------------------------------------
__device__ __forceinline__ float rsb_eval(int k, const float* __restrict__ w,
                                          float bias) {
  // dsc = -4 + k/256 (exact); x = dsc/1024 (exact).
  float x = (-4.f + (float)k * (1.f / 256.f)) * (1.f / 1024.f);
  float acc = bias;
  float s7 = 0.f, c7 = 1.f;
#pragma unroll
  for (int f = 0; f < 8; ++f) {
    float a = x * (float)(1 << f);  // pow2 scale: exact
    float s, c;
    sincosf(a, &s, &c);             // |a| <= 0.5 rad
    acc = fmaf(w[f], s, acc);
    acc = fmaf(w[NF + f], c, acc);
    if (f == 7) { s7 = s; c7 = c; }
  }
  float ss = s7, cc = c7;
#pragma unroll
  for (int f = 8; f < NF; ++f) {
    float ns = 2.f * ss * cc;             // sin(2a)
    float nc = fmaf(cc, cc, -(ss * ss));  // cos(2a)
    ss = ns;
    cc = nc;
    acc = fmaf(w[f], ss, acc);
    acc = fmaf(w[NF + f], cc, acc);
  }
  return acc;
}

__global__ void rsb_build_table(const float* __restrict__ w,
                                const float* __restrict__ bptr,
                                float2* __restrict__ tab) {
  int k = blockIdx.x * blockDim.x + threadIdx.x;
  if (k >= TABN) return;
  float bias = bptr[0];
  float g0 = rsb_eval(k, w, bias);
  float g1 = rsb_eval(k + 1, w, bias);
  tab[k] = make_float2(g0, g1 - g0);
}

// ---------------------------------------------------------------------------
// Main: one (b, 32-row, 256-col) tile per 256-thread block (round-1 shape).
// LDS: 16 KB table + i-rows -> 8 blocks/CU = 32 waves/CU (100% occupancy).
// Each thread: 4 consecutive j (float4 I/O), 8 i-rows.
// ---------------------------------------------------------------------------
__device__ __forceinline__ float rsb_elem(const float2* __restrict__ tab_s,
                                          float4 pi, float4 pj, bool valid) {
  float dx = pi.x - pj.x;
  float dy = pi.y - pj.y;
  float dz = pi.z - pj.z;
  float dt = pi.w - pj.w;
  // Exact numpy f32 op order: ((dt*dt - dx*dx) - dy*dy) - dz*dz, no FMA
  // contraction (light-cone cancellation must track the reference).
  float ds2 = __fsub_rn(
      __fsub_rn(__fsub_rn(__fmul_rn(dt, dt), __fmul_rn(dx, dx)),
                __fmul_rn(dy, dy)),
      __fmul_rn(dz, dz));
  float rr = sqrtf(fabsf(ds2) + 1e-12f);
  float dsv = __builtin_copysignf(rr, ds2);       // sign(0) diff ~1e-6, ok
  dsv = __builtin_amdgcn_fmed3f(dsv, -4.f, 4.f);  // clip
  float t = fmaf(dsv, (float)(TABN / 8), (float)(TABN / 2));  // [0, TABN]
  int it = (int)t;
  it = min(it, TABN - 1);
  float frac = t - (float)it;                     // ==1.0 when clamped high
  float2 bs = tab_s[it];                          // single ds_read_b64
  float g = fmaf(frac, bs.y, bs.x);
  return valid ? g : 0.f;
}

__global__ __launch_bounds__(256, 8) void rsb_main(
    const float* __restrict__ pos, const int* __restrict__ mask,
    const float2* __restrict__ tab, float* __restrict__ out, int S) {
  __shared__ float4 tab4_s[TABN / 2];  // 16 KB: TABN float2 as float4 pairs
  __shared__ float4 pi_s[32];
  __shared__ int mi_s[32];
  const float2* tab_s = (const float2*)tab4_s;

  const int tid = threadIdx.x;
  const int b = blockIdx.z;
  const int ibase = blockIdx.y * 32;
  const int jbase = blockIdx.x * 256;

  {
    const float4* t4 = (const float4*)tab;
#pragma unroll
    for (int r = 0; r < 4; ++r) tab4_s[r * 256 + tid] = t4[r * 256 + tid];
    if (tid < 32 && (ibase + tid) < S) {
      pi_s[tid] = ((const float4*)pos)[(size_t)b * S + ibase + tid];
      mi_s[tid] = mask[(size_t)b * S + ibase + tid];
    }
  }
  __syncthreads();

  const int tx = tid & 63;
  const int ty = tid >> 6;
  const int j4 = jbase + tx * 4;
  if (j4 >= S) return;

  const float4* pjp = (const float4*)pos + (size_t)b * S + j4;
  float4 pj0 = pjp[0];
  float4 pj1 = pjp[1];
  float4 pj2 = pjp[2];
  float4 pj3 = pjp[3];
  int4 mj = *(const int4*)(mask + (size_t)b * S + j4);

#pragma unroll
  for (int r = 0; r < 8; ++r) {
    int irow = r * 4 + ty;
    int i = ibase + irow;
    if (i >= S) break;  // uniform per wave (ty uniform within wave)
    float4 pi = pi_s[irow];
    bool mi = (mi_s[irow] != 0);
    float4 o;
    o.x = rsb_elem(tab_s, pi, pj0, mi && (mj.x != 0));
    o.y = rsb_elem(tab_s, pi, pj1, mi && (mj.y != 0));
    o.z = rsb_elem(tab_s, pi, pj2, mi && (mj.z != 0));
    o.w = rsb_elem(tab_s, pi, pj3, mi && (mj.w != 0));
    *(float4*)(out + ((size_t)b * S + i) * S + j4) = o;
  }
}

// ---------------------------------------------------------------------------
extern "C" void kernel_launch(void* const* d_in, const int* in_sizes, int n_in,
                              void* d_out, int out_size, void* d_ws,
                              size_t ws_size, hipStream_t stream) {
  const float* pos = (const float*)d_in[0];   // (B,S,4) f32
  const int* mask = (const int*)d_in[1];      // (B,S) int
  const float* w = (const float*)d_in[2];     // (1,32) f32
  const float* bb = (const float*)d_in[3];    // (1,) f32
  float* out = (float*)d_out;                 // (B,S,S) f32

  const int BS = in_sizes[1];                 // B*S
  const int S = (int)((long long)out_size / BS);
  const int B = BS / S;

  float2* tab = (float2*)d_ws;  // TABN float2 = 16 KB scratch

  rsb_build_table<<<(TABN + 255) / 256, 256, 0, stream>>>(w, bb, tab);

  dim3 grid((S + 255) / 256, (S + 31) / 32, B);
  rsb_main<<<grid, 256, 0, stream>>>(pos, mask, tab, out, S);
}

// Round 9
// 92.647 us; speedup vs baseline: 1.0318x; 1.0318x over previous
//
#include <hip/hip_runtime.h>
#include <hip/hip_bf16.h>

#define TABN 2048
#define NF 16

// ---------------------------------------------------------------------------
// Table: g(ds_clipped) = b + sum_f ws[f]*sin(ds/1024*2^f) + wc[f]*cos(...)
// over ds in [-4,4], TABN intervals. Entry k = {g(k), g(k+1)-g(k)}.
//
// NO libm: rounds 1-7 accounting showed 16 sincosf/thread costs ~28 us at
// this launch's near-zero occupancy (pointer-output + call overhead with no
// latency hiding). |a| <= 0.5 rad for f=0..7 by construction, so inline
// Taylor polynomials (sin err <= 5e-9, cos err <= 3e-10) beat sincosf in
// both speed (pure FMA straight-line) and accuracy. f=8..15 via double-angle
// recurrence (error amplification 2^8 * eps ~= 3e-5 -> negligible vs 0.0317
// threshold). Interp err at h=1/256: <= ~2e-3.
// ---------------------------------------------------------------------------
__device__ __forceinline__ void sincos_poly(float a, float* s, float* c) {
  // valid for |a| <= 0.5 rad
  float a2 = a * a;
  float sp = fmaf(a2, fmaf(a2, fmaf(a2, -1.f / 5040.f, 1.f / 120.f),
                           -1.f / 6.f), 1.f);
  *s = a * sp;
  *c = fmaf(a2, fmaf(a2, fmaf(a2, fmaf(a2, 1.f / 40320.f, -1.f / 720.f),
                              1.f / 24.f), -0.5f), 1.f);
}

__device__ __forceinline__ float rsb_eval(int k, const float* __restrict__ w,
                                          float bias) {
  // dsc = -4 + k/256 (exact); x = dsc/1024 (exact).
  float x = (-4.f + (float)k * (1.f / 256.f)) * (1.f / 1024.f);
  float acc = bias;
  float s7 = 0.f, c7 = 1.f;
#pragma unroll
  for (int f = 0; f < 8; ++f) {
    float a = x * (float)(1 << f);  // pow2 scale: exact; |a| <= 0.5
    float s, c;
    sincos_poly(a, &s, &c);
    acc = fmaf(w[f], s, acc);
    acc = fmaf(w[NF + f], c, acc);
    if (f == 7) { s7 = s; c7 = c; }
  }
  float ss = s7, cc = c7;
#pragma unroll
  for (int f = 8; f < NF; ++f) {
    float ns = 2.f * ss * cc;             // sin(2a)
    float nc = fmaf(cc, cc, -(ss * ss));  // cos(2a)
    ss = ns;
    cc = nc;
    acc = fmaf(w[f], ss, acc);
    acc = fmaf(w[NF + f], cc, acc);
  }
  return acc;
}

__global__ void rsb_build_table(const float* __restrict__ w,
                                const float* __restrict__ bptr,
                                float2* __restrict__ tab) {
  int k = blockIdx.x * blockDim.x + threadIdx.x;
  if (k >= TABN) return;
  float bias = bptr[0];
  float g0 = rsb_eval(k, w, bias);
  float g1 = rsb_eval(k + 1, w, bias);
  tab[k] = make_float2(g0, g1 - g0);
}

// ---------------------------------------------------------------------------
// Main: one (b, 32-row, 256-col) tile per 256-thread block.
// LDS: 16 KB table + i-rows -> 8 blocks/CU = 32 waves/CU (100% occupancy).
// Each thread: 4 consecutive j (float4 I/O), 8 i-rows.
// (Unchanged from round 7 — accounting puts main at ~10-12 us, write-bound.)
// ---------------------------------------------------------------------------
__device__ __forceinline__ float rsb_elem(const float2* __restrict__ tab_s,
                                          float4 pi, float4 pj, bool valid) {
  float dx = pi.x - pj.x;
  float dy = pi.y - pj.y;
  float dz = pi.z - pj.z;
  float dt = pi.w - pj.w;
  // Exact numpy f32 op order: ((dt*dt - dx*dx) - dy*dy) - dz*dz, no FMA
  // contraction (light-cone cancellation must track the reference).
  float ds2 = __fsub_rn(
      __fsub_rn(__fsub_rn(__fmul_rn(dt, dt), __fmul_rn(dx, dx)),
                __fmul_rn(dy, dy)),
      __fmul_rn(dz, dz));
  float rr = sqrtf(fabsf(ds2) + 1e-12f);
  float dsv = __builtin_copysignf(rr, ds2);       // sign(0) diff ~1e-6, ok
  dsv = __builtin_amdgcn_fmed3f(dsv, -4.f, 4.f);  // clip
  float t = fmaf(dsv, (float)(TABN / 8), (float)(TABN / 2));  // [0, TABN]
  int it = (int)t;
  it = min(it, TABN - 1);
  float frac = t - (float)it;                     // ==1.0 when clamped high
  float2 bs = tab_s[it];                          // single ds_read_b64
  float g = fmaf(frac, bs.y, bs.x);
  return valid ? g : 0.f;
}

__global__ __launch_bounds__(256, 8) void rsb_main(
    const float* __restrict__ pos, const int* __restrict__ mask,
    const float2* __restrict__ tab, float* __restrict__ out, int S) {
  __shared__ float4 tab4_s[TABN / 2];  // 16 KB: TABN float2 as float4 pairs
  __shared__ float4 pi_s[32];
  __shared__ int mi_s[32];
  const float2* tab_s = (const float2*)tab4_s;

  const int tid = threadIdx.x;
  const int b = blockIdx.z;
  const int ibase = blockIdx.y * 32;
  const int jbase = blockIdx.x * 256;

  {
    const float4* t4 = (const float4*)tab;
#pragma unroll
    for (int r = 0; r < 4; ++r) tab4_s[r * 256 + tid] = t4[r * 256 + tid];
    if (tid < 32 && (ibase + tid) < S) {
      pi_s[tid] = ((const float4*)pos)[(size_t)b * S + ibase + tid];
      mi_s[tid] = mask[(size_t)b * S + ibase + tid];
    }
  }
  __syncthreads();

  const int tx = tid & 63;
  const int ty = tid >> 6;
  const int j4 = jbase + tx * 4;
  if (j4 >= S) return;

  const float4* pjp = (const float4*)pos + (size_t)b * S + j4;
  float4 pj0 = pjp[0];
  float4 pj1 = pjp[1];
  float4 pj2 = pjp[2];
  float4 pj3 = pjp[3];
  int4 mj = *(const int4*)(mask + (size_t)b * S + j4);

#pragma unroll
  for (int r = 0; r < 8; ++r) {
    int irow = r * 4 + ty;
    int i = ibase + irow;
    if (i >= S) break;  // uniform per wave (ty uniform within wave)
    float4 pi = pi_s[irow];
    bool mi = (mi_s[irow] != 0);
    float4 o;
    o.x = rsb_elem(tab_s, pi, pj0, mi && (mj.x != 0));
    o.y = rsb_elem(tab_s, pi, pj1, mi && (mj.y != 0));
    o.z = rsb_elem(tab_s, pi, pj2, mi && (mj.z != 0));
    o.w = rsb_elem(tab_s, pi, pj3, mi && (mj.w != 0));
    *(float4*)(out + ((size_t)b * S + i) * S + j4) = o;
  }
}

// ---------------------------------------------------------------------------
extern "C" void kernel_launch(void* const* d_in, const int* in_sizes, int n_in,
                              void* d_out, int out_size, void* d_ws,
                              size_t ws_size, hipStream_t stream) {
  const float* pos = (const float*)d_in[0];   // (B,S,4) f32
  const int* mask = (const int*)d_in[1];      // (B,S) int
  const float* w = (const float*)d_in[2];     // (1,32) f32
  const float* bb = (const float*)d_in[3];    // (1,) f32
  float* out = (float*)d_out;                 // (B,S,S) f32

  const int BS = in_sizes[1];                 // B*S
  const int S = (int)((long long)out_size / BS);
  const int B = BS / S;

  float2* tab = (float2*)d_ws;  // TABN float2 = 16 KB scratch

  rsb_build_table<<<(TABN + 255) / 256, 256, 0, stream>>>(w, bb, tab);

  dim3 grid((S + 255) / 256, (S + 31) / 32, B);
  rsb_main<<<grid, 256, 0, stream>>>(pos, mask, tab, out, S);
}